// Round 1
// baseline (3193.559 us; speedup 1.0000x reference)
//
#include <hip/hip_runtime.h>
#include <hip/hip_bf16.h>

// SNN forward for MI355X (gfx950).
// Key algebraic facts exploited:
//  - TAU1 == 1.0  =>  v1 <- a1 exactly (stateless): s1 = (a1 >= TH1).
//  - s1 is binary -> bf16-exact; conv2 runs on bf16 MFMA.
//  - Only sum_{t,l} s2 is needed -> accumulate scalar counts, never store spikes.

#define NB    64
#define NCIN  12
#define NC1   128
#define NC2   256
#define NKW   9
#define NT    20
#define NL    2048
#define GAINF 3.0f
#define THF   0.02f

typedef __bf16 bf16x8 __attribute__((ext_vector_type(8)));
typedef float  f32x4  __attribute__((ext_vector_type(4)));

__device__ __forceinline__ unsigned short f2bf(float f) {
  __hip_bfloat16 h = __float2bfloat16(f);
  return __builtin_bit_cast(unsigned short, h);
}

// ---------------- setup: W1 -> [c1][kd(128, zero-padded)] bf16 ; W2 -> [k][c2][c1] bf16
__global__ void snn_wsetup_kernel(const float* __restrict__ W1, const float* __restrict__ W2,
                                  unsigned short* __restrict__ w1t, unsigned short* __restrict__ w2t) {
  int idx = blockIdx.x * 256 + threadIdx.x;
  if (idx < 9 * 256 * 128) {
    int c1 = idx & 127;
    int c2 = (idx >> 7) & 255;
    int k  = idx >> 15;
    w2t[idx] = f2bf(W2[((size_t)c2 * 128 + c1) * 9 + k]);
  }
  if (idx < 128 * 128) {
    int c1 = idx >> 7, kd = idx & 127;
    float v = 0.f;
    if (kd < 108) {
      int cin = kd / 9, kk = kd - cin * 9;
      v = W1[((size_t)c1 * 12 + cin) * 9 + kk];
    }
    w1t[idx] = f2bf(v);
  }
}

// ---------------- conv1 + threshold: writes s1[b][l][c1] (bf16 0/1), one (b, l-tile of 128) per block
__global__ __launch_bounds__(256, 2) void snn_conv1_kernel(
    const float* __restrict__ x, const float* __restrict__ b1,
    const unsigned short* __restrict__ w1t, unsigned short* __restrict__ s1, int t) {
  __shared__ alignas(16) unsigned short ldsB[128 * 128];  // im2col [n=l_local][kd] swizzled
  __shared__ alignas(16) unsigned short ldsA[128 * 128];  // W1T [c1][kd] swizzled
  __shared__ float b1s[128];

  const int tid  = threadIdx.x;
  const int lane = tid & 63;
  const int wv   = tid >> 6;
  const int wm   = wv >> 1, wn = wv & 1;
  const int hi   = lane >> 4, lo = lane & 15;
  const int b    = blockIdx.x >> 4;
  const int l0   = (blockIdx.x & 15) << 7;

  // stage A (W1T) with swizzle: 32768 B
  {
    const uint4* gA = (const uint4*)w1t;
#pragma unroll
    for (int i = 0; i < 8; ++i) {
      int idx = tid + i * 256;
      unsigned off = (unsigned)idx * 16u;
      unsigned row = off >> 8;
      *(uint4*)((char*)ldsA + (off ^ ((row & 7u) << 4))) = gA[idx];
    }
  }
  if (tid < 128) b1s[tid] = b1[tid];

  // zero im2col cols 108..127 (A is zero there too, but avoid NaN garbage in B)
  for (int i = tid; i < 128 * 20; i += 256) {
    int n = i / 20, c = 108 + (i - n * 20);
    *(unsigned short*)((char*)ldsB + ((unsigned)(n * 256) + (((unsigned)c * 2u) ^ (((unsigned)n & 7u) << 4)))) = 0;
  }
  // build im2col: B[n][cin*9+k] = x[b][cin][l0+n+k-4][t]
  for (int e = tid; e < NCIN * 136; e += 256) {
    int cin = e / 136, i = e - cin * 136;
    int l = l0 - 4 + i;
    float xv = 0.f;
    if (l >= 0 && l < NL) xv = x[(((size_t)b * NCIN + cin) * NL + l) * NT + t];
    unsigned short hv = f2bf(xv);
    int kd0 = cin * 9;
#pragma unroll
    for (int k = 0; k < 9; ++k) {
      int n = i - k;
      if (n >= 0 && n < 128) {
        *(unsigned short*)((char*)ldsB + ((unsigned)(n * 256) + (((unsigned)(kd0 + k) * 2u) ^ (((unsigned)n & 7u) << 4)))) = hv;
      }
    }
  }
  __syncthreads();

  f32x4 acc[4][4];
#pragma unroll
  for (int mf = 0; mf < 4; ++mf)
#pragma unroll
    for (int nf = 0; nf < 4; ++nf) acc[mf][nf] = (f32x4){0.f, 0.f, 0.f, 0.f};

  for (int chunk = 0; chunk < 4; ++chunk) {
    const unsigned kd2 = (unsigned)(chunk * 32 + hi * 8) * 2u;
    bf16x8 af[4], bfr[4];
#pragma unroll
    for (int mf = 0; mf < 4; ++mf) {
      int r = wm * 64 + mf * 16 + lo;
      af[mf] = *(const bf16x8*)((const char*)ldsA + ((unsigned)(r * 256) + (kd2 ^ (((unsigned)r & 7u) << 4))));
    }
#pragma unroll
    for (int nf = 0; nf < 4; ++nf) {
      int r = wn * 64 + nf * 16 + lo;
      bfr[nf] = *(const bf16x8*)((const char*)ldsB + ((unsigned)(r * 256) + (kd2 ^ (((unsigned)r & 7u) << 4))));
    }
#pragma unroll
    for (int mf = 0; mf < 4; ++mf)
#pragma unroll
      for (int nf = 0; nf < 4; ++nf)
        acc[mf][nf] = __builtin_amdgcn_mfma_f32_16x16x32_bf16(af[mf], bfr[nf], acc[mf][nf], 0, 0, 0);
  }
  __syncthreads();

  // spike + bounce into ldsB as swizzled [l_local][c1] for coalesced copy-out
#pragma unroll
  for (int mf = 0; mf < 4; ++mf) {
    int c1b = wm * 64 + mf * 16 + hi * 4;
#pragma unroll
    for (int nf = 0; nf < 4; ++nf) {
      int lrow = wn * 64 + nf * 16 + lo;
      float a0 = GAINF * (acc[mf][nf][0] + b1s[c1b + 0]);
      float a1v = GAINF * (acc[mf][nf][1] + b1s[c1b + 1]);
      float a2v = GAINF * (acc[mf][nf][2] + b1s[c1b + 2]);
      float a3v = GAINF * (acc[mf][nf][3] + b1s[c1b + 3]);
      uint2 pv;
      pv.x = (a0 >= THF ? 0x3F80u : 0u) | ((a1v >= THF ? 0x3F80u : 0u) << 16);
      pv.y = (a2v >= THF ? 0x3F80u : 0u) | ((a3v >= THF ? 0x3F80u : 0u) << 16);
      *(uint2*)((char*)ldsB + ((unsigned)(lrow * 256) + (((unsigned)c1b * 2u) ^ (((unsigned)lrow & 7u) << 4)))) = pv;
    }
  }
  __syncthreads();

  uint4* gS = (uint4*)(s1 + ((size_t)b * NL + l0) * NC1);
#pragma unroll
  for (int i = 0; i < 8; ++i) {
    int idx = tid + i * 256;
    unsigned off = (unsigned)idx * 16u;
    unsigned row = off >> 8;
    gS[idx] = *(const uint4*)((const char*)ldsB + (off ^ ((row & 7u) << 4)));
  }
}

// ---------------- conv2 + LIF2 + count accumulation. One (b, c2-half, l-tile of 128) per block.
__global__ __launch_bounds__(256, 2) void snn_conv2_kernel(
    const unsigned short* __restrict__ s1, const unsigned short* __restrict__ w2t,
    const float* __restrict__ b2, float* __restrict__ v2, float* __restrict__ counts) {
  __shared__ alignas(16) unsigned short ldsS[136 * 128];  // s1 tile rows l0-4..l0+131, swizzled
  __shared__ alignas(16) unsigned short ldsW[128 * 128];  // W2 tap tile [c2_local][c1], swizzled
  __shared__ float b2s[128];

  const int tid  = threadIdx.x;
  const int lane = tid & 63;
  const int wv   = tid >> 6;
  const int wm   = wv >> 1, wn = wv & 1;
  const int hi   = lane >> 4, lo = lane & 15;
  const int b    = blockIdx.x >> 5;
  const int r5   = blockIdx.x & 31;
  const int c2b  = r5 >> 4;
  const int l0   = (r5 & 15) << 7;

  // stage s1 tile (34816 B = 2176 x uint4); out-of-range rows (only edge tiles) get zeros
  {
    const char* gB = (const char*)s1 + (((size_t)b * NL + l0) * NC1 - 4 * NC1) * 2;
    for (int idx = tid; idx < 2176; idx += 256) {
      unsigned off = (unsigned)idx * 16u;
      unsigned row = off >> 8;
      int l = l0 - 4 + (int)row;
      uint4 v;
      if (l >= 0 && l < NL) v = *(const uint4*)(gB + off);
      else { v.x = 0; v.y = 0; v.z = 0; v.w = 0; }
      *(uint4*)((char*)ldsS + (off ^ ((row & 7u) << 4))) = v;
    }
  }
  if (tid < 128) b2s[tid] = b2[c2b * 128 + tid];

  f32x4 acc[4][4];
#pragma unroll
  for (int mf = 0; mf < 4; ++mf)
#pragma unroll
    for (int nf = 0; nf < 4; ++nf) acc[mf][nf] = (f32x4){0.f, 0.f, 0.f, 0.f};

  for (int tap = 0; tap < 9; ++tap) {
    __syncthreads();  // first iter: covers s1/b2 staging; later: protect ldsW overwrite
    const uint4* gW = (const uint4*)(w2t + ((size_t)tap * 256 + c2b * 128) * 128);
#pragma unroll
    for (int i = 0; i < 8; ++i) {
      int idx = tid + i * 256;
      unsigned off = (unsigned)idx * 16u;
      unsigned row = off >> 8;
      *(uint4*)((char*)ldsW + (off ^ ((row & 7u) << 4))) = gW[idx];
    }
    __syncthreads();
    for (int chunk = 0; chunk < 4; ++chunk) {
      const unsigned kd2 = (unsigned)(chunk * 32 + hi * 8) * 2u;
      bf16x8 af[4], bfr[4];
#pragma unroll
      for (int mf = 0; mf < 4; ++mf) {
        int rr = wm * 64 + mf * 16 + lo;
        af[mf] = *(const bf16x8*)((const char*)ldsW + ((unsigned)(rr * 256) + (kd2 ^ (((unsigned)rr & 7u) << 4))));
      }
#pragma unroll
      for (int nf = 0; nf < 4; ++nf) {
        int rr = wn * 64 + nf * 16 + lo + tap;  // tap shift: s1[l + tap - 4] is tile row n + tap
        bfr[nf] = *(const bf16x8*)((const char*)ldsS + ((unsigned)(rr * 256) + (kd2 ^ (((unsigned)rr & 7u) << 4))));
      }
#pragma unroll
      for (int mf = 0; mf < 4; ++mf)
#pragma unroll
        for (int nf = 0; nf < 4; ++nf)
          acc[mf][nf] = __builtin_amdgcn_mfma_f32_16x16x32_bf16(af[mf], bfr[nf], acc[mf][nf], 0, 0, 0);
    }
  }

  // epilogue: LIF2 (v2 state in global), spike counting
  int cnt[4][4];
#pragma unroll
  for (int mf = 0; mf < 4; ++mf)
#pragma unroll
    for (int j = 0; j < 4; ++j) cnt[mf][j] = 0;

  const float inv_tau2 = 1.0f / 0.9f;
#pragma unroll
  for (int mf = 0; mf < 4; ++mf) {
#pragma unroll
    for (int nf = 0; nf < 4; ++nf) {
      int lcol = l0 + wn * 64 + nf * 16 + lo;
#pragma unroll
      for (int j = 0; j < 4; ++j) {
        int c2loc = wm * 64 + mf * 16 + hi * 4 + j;
        size_t idx = ((size_t)b * NC2 + c2b * 128 + c2loc) * NL + lcol;
        float a2 = GAINF * (acc[mf][nf][j] + b2s[c2loc]);
        float vo = v2[idx];
        float vn = vo + (a2 - vo) * inv_tau2;
        int sp = (vn >= THF) ? 1 : 0;
        v2[idx] = sp ? 0.f : vn;
        cnt[mf][j] += sp;
      }
    }
  }
#pragma unroll
  for (int mf = 0; mf < 4; ++mf)
#pragma unroll
    for (int j = 0; j < 4; ++j) {
      int c = cnt[mf][j];
      c += __shfl_xor(c, 1);
      c += __shfl_xor(c, 2);
      c += __shfl_xor(c, 4);
      c += __shfl_xor(c, 8);
      if (lo == 0) {
        int c2g = c2b * 128 + wm * 64 + mf * 16 + hi * 4 + j;
        atomicAdd(&counts[b * NC2 + c2g], (float)c);
      }
    }
}

// ---------------- final FC: out[b][cls] = bfc[cls] + (1/(T*L)) * sum_c2 counts[b][c2]*Wfc[cls][c2]
__global__ void snn_fc_kernel(const float* __restrict__ counts, const float* __restrict__ Wfc,
                              const float* __restrict__ bfc, float* __restrict__ out) {
  int tid = threadIdx.x;  // 256 = 64 b x 4 cls
  int b = tid >> 2, cls = tid & 3;
  float s = 0.f;
  for (int c = 0; c < 256; ++c) s += counts[b * 256 + c] * Wfc[cls * 256 + c];
  out[tid] = s * (1.0f / ((float)NT * (float)NL)) + bfc[cls];
}

extern "C" void kernel_launch(void* const* d_in, const int* in_sizes, int n_in,
                              void* d_out, int out_size, void* d_ws, size_t ws_size,
                              hipStream_t stream) {
  const float* x   = (const float*)d_in[0];
  const float* W1  = (const float*)d_in[1];
  const float* b1  = (const float*)d_in[2];
  const float* W2  = (const float*)d_in[3];
  const float* b2  = (const float*)d_in[4];
  const float* Wfc = (const float*)d_in[5];
  const float* bfc = (const float*)d_in[6];
  float* out = (float*)d_out;
  char* ws = (char*)d_ws;

  const size_t SZ_V2  = (size_t)NB * NC2 * NL * 4;        // 134,217,728
  const size_t SZ_S1  = (size_t)NB * NL * NC1 * 2;        // 33,554,432
  const size_t SZ_W2T = (size_t)9 * 256 * 128 * 2;        // 589,824
  const size_t SZ_W1T = (size_t)128 * 128 * 2;            // 32,768
  const size_t SZ_CNT = (size_t)NB * NC2 * 4;             // 65,536

  const size_t OFF_V2  = 0;
  const size_t OFF_S1  = OFF_V2 + SZ_V2;
  const size_t OFF_W2T = OFF_S1 + SZ_S1;
  const size_t OFF_W1T = OFF_W2T + SZ_W2T;
  const size_t OFF_CNT = OFF_W1T + SZ_W1T;
  const size_t NEEDED  = OFF_CNT + SZ_CNT;
  if (ws_size < NEEDED) return;  // cannot run without scratch; fail loudly via wrong output

  float* v2 = (float*)(ws + OFF_V2);
  unsigned short* s1  = (unsigned short*)(ws + OFF_S1);
  unsigned short* w2t = (unsigned short*)(ws + OFF_W2T);
  unsigned short* w1t = (unsigned short*)(ws + OFF_W1T);
  float* counts = (float*)(ws + OFF_CNT);

  hipMemsetAsync(v2, 0, SZ_V2, stream);
  hipMemsetAsync(counts, 0, SZ_CNT, stream);

  snn_wsetup_kernel<<<1152, 256, 0, stream>>>(W1, W2, w1t, w2t);

  for (int t = 0; t < NT; ++t) {
    snn_conv1_kernel<<<NB * (NL / 128), 256, 0, stream>>>(x, b1, w1t, s1, t);
    snn_conv2_kernel<<<NB * 2 * (NL / 128), 256, 0, stream>>>(s1, w2t, b2, v2, counts);
  }

  snn_fc_kernel<<<1, 256, 0, stream>>>(counts, Wfc, bfc, out);
}